// Round 5
// baseline (299.181 us; speedup 1.0000x reference)
//
#include <hip/hip_runtime.h>

// ---------------------------------------------------------------------------
// Problem constants
// ---------------------------------------------------------------------------
#define BATCH   16384
#define NF      16          // N_FEAT
#define OUTD    256         // OUT_DIM
#define NNEW    4828        // generated monomials (deg 2..4)
#define MTOT    4844        // 16 + 4828
#define KPAD    4864        // 76 * 64
#define KPAD2   (KPAD/2)
#define NCHUNK  76
#define BM      32          // rows per block
#define TROW    155         // T row stride floats: 27 mod 32 -> conflict-free gathers
#define ASTR    72          // As row stride ushorts: 144 B (9 x 16B granules-worth)

// ---------------------------------------------------------------------------
// Compile-time expansion tables
// ---------------------------------------------------------------------------
struct ExpTab { unsigned jp[NNEW]; int total; };

constexpr ExpTab make_tab() {
    ExpTab t{};
    int Id[NF] = {};
    for (int i = 0; i < NF; ++i) Id[i] = i;
    int M = NF, idx = 0;
    for (int pass = 0; pass < 3; ++pass) {
        const int hi = Id[NF - 1];
        for (int j = 0; j < NF; ++j) {
            const int lo = Id[j];
            for (int p = lo; p <= hi; ++p) t.jp[idx++] = ((unsigned)j << 16) | (unsigned)p;
            Id[j] = M;
            M += hi - lo + 1;
        }
    }
    t.total = M;
    return t;
}
constexpr ExpTab h_tab = make_tab();
static_assert(h_tab.total == MTOT, "M_TOTAL");

// 2-factor table: epd[m] = T2[L]*T2[R], T2 = {16 deg1, 136 deg2, [152]=1, [153]=0}
struct PkTab {
    alignas(16) unsigned e[KPAD];   // L | R<<16 (word offsets within a T row)
    unsigned b2[136];               // j | p<<16 (deg1 offsets, to build deg2)
};

constexpr PkTab make_pk() {
    ExpTab t = make_tab();
    int d2[NF][NF] = {};
    {
        int m = NF;
        for (int j = 0; j < NF; ++j)
            for (int p = j; p < NF; ++p) d2[j][p] = m++;
    }
    PkTab pk{};
    for (int q = 0; q < 136; ++q) {
        unsigned jp = t.jp[q];
        pk.b2[q] = (jp >> 16) | ((jp & 0xffffu) << 16);
    }
    for (int m = 0; m < KPAD; ++m) {
        if (m >= MTOT) { pk.e[m] = 153u | (153u << 16); continue; }
        int f[4] = {}, n = 0, cur = m;
        while (cur >= NF) {
            unsigned jp = t.jp[cur - NF];
            f[n++] = (int)(jp >> 16);
            cur = (int)(jp & 0xffffu);
        }
        f[n++] = cur;
        for (int i = 0; i < n; ++i)
            for (int k = i + 1; k < n; ++k)
                if (f[k] < f[i]) { int tmp = f[i]; f[i] = f[k]; f[k] = tmp; }
        unsigned L, R;
        if      (n == 1) { L = (unsigned)f[0];           R = 152u; }
        else if (n == 2) { L = (unsigned)d2[f[0]][f[1]]; R = 152u; }
        else if (n == 3) { L = (unsigned)d2[f[0]][f[1]]; R = (unsigned)f[2]; }
        else             { L = (unsigned)d2[f[0]][f[1]]; R = (unsigned)d2[f[2]][f[3]]; }
        pk.e[m] = L | (R << 16);
    }
    return pk;
}
constexpr bool pk_ok() {
    PkTab p = make_pk();
    for (int m = 0; m < KPAD; ++m)
        if ((p.e[m] & 0xffffu) > 153u || (p.e[m] >> 16) > 153u) return false;
    return p.e[16] == (16u | (152u << 16));
}
static_assert(pk_ok(), "2-factor decomposition");

__device__ const PkTab g_pk = make_pk();

// ---------------------------------------------------------------------------
// Helpers
// ---------------------------------------------------------------------------
typedef __attribute__((ext_vector_type(8))) short    bf16x8;
typedef __attribute__((ext_vector_type(4))) float    f32x4;
typedef __attribute__((ext_vector_type(4))) unsigned uint4v;

__device__ inline unsigned bfpack2(float lo, float hi) {
    unsigned ul = __float_as_uint(lo), uh = __float_as_uint(hi);
    ul = (ul + 0x7fffu + ((ul >> 16) & 1u)) >> 16;
    uh = (uh + 0x7fffu + ((uh >> 16) & 1u)) & 0xffff0000u;
    return ul | uh;
}

// ---------------------------------------------------------------------------
// W fp32 [256][4844] -> bf16 [256][KPAD] (zero-padded)
// ---------------------------------------------------------------------------
__global__ __launch_bounds__(256) void wconv_kernel(
    const float* __restrict__ W, unsigned* __restrict__ Wb)
{
    const int r = blockIdx.x;
    for (int i = threadIdx.x; i < KPAD2; i += 256) {
        const int c0 = 2 * i, c1 = 2 * i + 1;
        const float f0 = (c0 < MTOT) ? W[(size_t)r * MTOT + c0] : 0.f;
        const float f1 = (c1 < MTOT) ? W[(size_t)r * MTOT + c1] : 0.f;
        Wb[(size_t)r * KPAD2 + i] = bfpack2(f0, f1);
    }
}

// ---------------------------------------------------------------------------
// Fused: tanh -> expansion (waves 0-1) -> MFMA GEMM (waves 2-5)
//   BM=32, BN=256, BK=64, grid 512 (2 blocks/CU), 384 thr.
//   2-slot As double buffer, 1 barrier per chunk, As granule-swizzled.
// ---------------------------------------------------------------------------
__global__ __launch_bounds__(384, 3) void fused_kernel(
    const float* __restrict__ x,
    const unsigned short* __restrict__ Wb,
    const float* __restrict__ bias,
    float* __restrict__ C)
{
    __shared__ float T[BM * TROW];                        // 19.8 KB
    __shared__ alignas(16) unsigned short As[2][BM * ASTR]; // 9.2 KB
    const int t   = threadIdx.x;
    const int l   = t & 63;
    const int wid = t >> 6;                   // 0-1 producers, 2-5 consumers
    const size_t m0 = (size_t)blockIdx.x * BM;

    // --- producer pk prefetch (before prologue, hides L2 latency) --------
    const int pr = l & 31;                    // producer: row
    const int ph = l >> 5;                    // producer: col-half
    uint4v eA[4], eB[4];
    auto loadPk = [&](int c, uint4v (&e4)[4]) {
        const uint4v* pe = (const uint4v*)(g_pk.e + c * 64 + wid * 32 + ph * 16);
#pragma unroll
        for (int i = 0; i < 4; ++i) e4[i] = pe[i];
    };
    if (wid < 2) loadPk(0, eA);

    // --- consumer state (B prefetch also before prologue) ----------------
    const int w  = wid - 2;                   // 0..3: 64-col band
    const int lr = l & 15, lk = l >> 4;
    const unsigned short* wbase = Wb + (size_t)(w * 64 + lr) * KPAD + lk * 8;
    bf16x8 bA[4][2], bB[4][2];
    auto prefB = [&](int c, bf16x8 (&bf)[4][2]) {
#pragma unroll
        for (int ni = 0; ni < 4; ++ni)
#pragma unroll
            for (int ks = 0; ks < 2; ++ks)
                bf[ni][ks] = *(const bf16x8*)(wbase + (size_t)ni * 16 * KPAD
                                              + (size_t)c * 64 + ks * 32);
    };
    if (wid >= 2) prefB(0, bA);

    // --- prologue: deg1 tanh + pads (threads 0-255) -----------------------
    if (t < 256) {
#pragma unroll
        for (int i = 0; i < 2; ++i) {
            const int v = t * 2 + i;          // 0..511
            const int r = v >> 4, fq = v & 15;
            T[r * TROW + fq] = tanhf(x[(m0 + r) * NF + fq]);
        }
        if (t < BM) { T[t * TROW + 152] = 1.0f; T[t * TROW + 153] = 0.0f; }
    }
    __syncthreads();
    // --- deg2 (threads 0-255: row t>>3, slice t&7) ------------------------
    if (t < 256) {
        const int r = t >> 3, s = t & 7, base = r * TROW;
#pragma unroll
        for (int i = 0; i < 17; ++i) {
            const int q = s + 8 * i;
            const unsigned e = g_pk.b2[q];
            T[base + NF + q] = T[base + (e & 0xffffu)] * T[base + (e >> 16)];
        }
    }
    __syncthreads();

    // --- producer: expand 16 cols for own row; swizzled granule store -----
    const int pbase = pr * TROW;
    const int g0   = wid * 4 + ph * 2;                    // first granule
    const int gswz = (pr >> 3) & 3;                       // row-derived XOR
    const int wo0  = pr * ASTR + ((g0    ) ^ gswz) * 8;   // ushort offsets
    const int wo1  = pr * ASTR + ((g0 + 1) ^ gswz) * 8;
    auto expand = [&](int slot, const uint4v (&e4)[4]) {
        float v[16];
#pragma unroll
        for (int i = 0; i < 16; ++i) {
            const unsigned e = e4[i >> 2][i & 3];
            v[i] = T[pbase + (e & 0xffffu)] * T[pbase + (e >> 16)];
        }
        uint4v o0, o1;
        o0[0] = bfpack2(v[0],  v[1]);  o0[1] = bfpack2(v[2],  v[3]);
        o0[2] = bfpack2(v[4],  v[5]);  o0[3] = bfpack2(v[6],  v[7]);
        o1[0] = bfpack2(v[8],  v[9]);  o1[1] = bfpack2(v[10], v[11]);
        o1[2] = bfpack2(v[12], v[13]); o1[3] = bfpack2(v[14], v[15]);
        *(uint4v*)&As[slot][wo0] = o0;
        *(uint4v*)&As[slot][wo1] = o1;
    };

    f32x4 acc[2][4];
#pragma unroll
    for (int i = 0; i < 2; ++i)
#pragma unroll
        for (int j = 0; j < 4; ++j) acc[i][j] = (f32x4){0.f, 0.f, 0.f, 0.f};

    auto domfma = [&](int slot, bf16x8 (&bf)[4][2]) {
        bf16x8 af[2][2];
#pragma unroll
        for (int mi = 0; mi < 2; ++mi)
#pragma unroll
            for (int ks = 0; ks < 2; ++ks) {
                const int row = mi * 16 + lr;
                const int sg  = (ks * 4 + lk) ^ ((row >> 3) & 3);
                af[mi][ks] = *(const bf16x8*)&As[slot][row * ASTR + sg * 8];
            }
        __builtin_amdgcn_s_setprio(1);
#pragma unroll
        for (int ks = 0; ks < 2; ++ks)
#pragma unroll
            for (int mi = 0; mi < 2; ++mi)
#pragma unroll
                for (int ni = 0; ni < 4; ++ni)
                    acc[mi][ni] = __builtin_amdgcn_mfma_f32_16x16x32_bf16(
                        af[mi][ks], bf[ni][ks], acc[mi][ni], 0, 0, 0);
        __builtin_amdgcn_s_setprio(0);
    };

    // --- pre-loop: chunk 0 staged / B1 prefetched -------------------------
    if (wid < 2) { expand(0, eA); loadPk(1, eB); }
    __syncthreads();

    // --- main loop: 2 chunks / iter, 1 barrier / chunk --------------------
    for (int it = 0; it < NCHUNK / 2; ++it) {
        const int c = 2 * it;
        if (wid < 2) {
            if (c + 2 < NCHUNK) loadPk(c + 2, eA);
            expand(1, eB);                    // chunk c+1 -> slot 1
        } else {
            prefB(c + 1, bB);
            domfma(0, bA);                    // chunk c (slot 0)
        }
        __syncthreads();
        if (wid < 2) {
            if (c + 3 < NCHUNK) loadPk(c + 3, eB);
            if (c + 2 < NCHUNK) expand(0, eA); // chunk c+2 -> slot 0
        } else {
            if (c + 2 < NCHUNK) prefB(c + 2, bA);
            domfma(1, bB);                    // chunk c+1 (slot 1)
        }
        __syncthreads();
    }

    // --- epilogue: consumers store bias+relu ------------------------------
    if (wid >= 2) {
#pragma unroll
        for (int ni = 0; ni < 4; ++ni) {
            const int col = w * 64 + ni * 16 + lr;
            const float bv = bias[col];
#pragma unroll
            for (int mi = 0; mi < 2; ++mi) {
                const size_t r0 = m0 + mi * 16 + lk * 4;
#pragma unroll
                for (int j = 0; j < 4; ++j)
                    C[(r0 + j) * OUTD + col] = fmaxf(acc[mi][ni][j] + bv, 0.f);
            }
        }
    }
}

// ---------------------------------------------------------------------------
// Launch
// ---------------------------------------------------------------------------
extern "C" void kernel_launch(void* const* d_in, const int* in_sizes, int n_in,
                              void* d_out, int out_size, void* d_ws, size_t ws_size,
                              hipStream_t stream)
{
    const float* x    = (const float*)d_in[0];   // [16384,16,1]
    const float* W    = (const float*)d_in[1];   // [256,4844]
    const float* bias = (const float*)d_in[2];   // [256,1]
    float* out        = (float*)d_out;           // [16384,256,1]

    unsigned* Wb = (unsigned*)d_ws;              // 2.49 MB bf16 W copy
    wconv_kernel<<<OUTD, 256, 0, stream>>>(W, Wb);
    fused_kernel<<<BATCH / BM, 384, 0, stream>>>(
        x, (const unsigned short*)Wb, bias, out);
}

// Round 6
// 151.740 us; speedup vs baseline: 1.9717x; 1.9717x over previous
//
#include <hip/hip_runtime.h>

// ---------------------------------------------------------------------------
// Problem constants
// ---------------------------------------------------------------------------
#define BATCH   16384
#define NF      16
#define OUTD    256
#define MTOT    4844
#define NK      5120        // permuted+padded K (80 chunks of 64)
#define NCHUNK  80
#define NIV     20          // intervals of 4 chunks
#define TROW    155         // T row stride (words): odd -> conflict-free column reads
#define NCREAL  5080        // real+group-padded columns

// ---------------------------------------------------------------------------
// Compile-time plan: permuted K-axis of (L, R-run) groups
//   T row layout: for c=0..15: [x_c, d2[c][c..15]]; [152]=1, [153]=[154]=0
//   group (a<=b): L = pos(d2[a][b]), R over [pos_x(b), 152)  (deg3+deg4)
//   unit group:   L = 152,           R over [0,152)          (deg1+deg2)
// ---------------------------------------------------------------------------
struct Plan {
    unsigned cplan[NCHUNK * 16];  // per quad: L | R0<<16 (pad: 153|152<<16)
    short    perm[NK];            // original column index or -1 (W=0)
    unsigned d2t[136];            // srcA | srcB<<10 | dst<<20 (word offsets)
    int ncols; int nreal; bool ok;
};

constexpr Plan make_plan() {
    Plan P{};
    int posx[17] = {};
    for (int c = 0; c <= 16; ++c) posx[c] = 17 * c - c * (c - 1) / 2;
    int S1t[16], Id2t[16], b3[16], b4[16];
    for (int j = 0; j < 16; ++j) { S1t[j] = 16 * j - j * (j - 1) / 2; Id2t[j] = 16 + S1t[j]; }
    { int s = 152; for (int j = 0; j < 16; ++j) { b3[j] = s; s += 152 - Id2t[j]; } }
    { int s = 968; for (int j = 0; j < 16; ++j) { b4[j] = s; s += 968 - b3[j]; } }
    { int idx = 0;
      for (int c = 0; c < 16; ++c)
        for (int d = c; d < 16; ++d)
            P.d2t[idx++] = (unsigned)posx[c] | ((unsigned)posx[d] << 10)
                         | ((unsigned)(posx[c] + 1 + (d - c)) << 20);
    }
    for (int q = 0; q < NCHUNK * 16; ++q) P.cplan[q] = 153u | (152u << 16);
    for (int k = 0; k < NK; ++k) P.perm[k] = -1;

    int k = 0;
    for (int p = 0; p < 152; ++p) {                       // unit group
        if ((k & 3) == 0) P.cplan[k >> 2] = 152u | ((unsigned)p << 16);
        int c = 0; while (posx[c + 1] <= p) ++c;
        int m;
        if (p == posx[c]) m = c;                          // deg1
        else { int d = c + (p - posx[c] - 1); m = 16 + S1t[c] + (d - c); }  // deg2
        P.perm[k++] = (short)m;
    }
    for (int b = 0; b < 16; ++b)
      for (int a = 0; a <= b; ++a) {                      // group (a,b)
        const int L = posx[a] + 1 + (b - a);
        const int st = posx[b], len = 152 - st, plen = (len + 3) & ~3;
        for (int off = 0; off < plen; ++off) {
            if ((k & 3) == 0) P.cplan[k >> 2] = (unsigned)L | ((unsigned)(st + off) << 16);
            if (off < len) {
                const int p = st + off;
                int c = 0; while (posx[c + 1] <= p) ++c;
                int m;
                if (p == posx[c]) {                        // deg3 {a,b,c}
                    m = b3[a] + (16 + S1t[b] + (c - b)) - Id2t[a];
                } else {                                   // deg4 {a,b,c,d}
                    const int d = c + (p - posx[c] - 1);
                    const int o3 = b3[b] + (16 + S1t[c] + (d - c)) - Id2t[b];
                    m = b4[a] + o3 - b3[a];
                }
                P.perm[k] = (short)m;
            }
            ++k;
        }
      }
    P.ncols = k;
    unsigned bm[152] = {};
    int cnt = 0; bool ok = (k == NCREAL);
    for (int kk = 0; kk < NK; ++kk) {
        const int m = P.perm[kk];
        if (m >= 0) {
            if (m >= MTOT || (bm[m >> 5] & (1u << (m & 31)))) { ok = false; break; }
            bm[m >> 5] |= 1u << (m & 31); ++cnt;
        }
    }
    if (cnt != MTOT) ok = false;
    P.nreal = cnt; P.ok = ok;
    return P;
}
constexpr Plan h_plan = make_plan();
static_assert(h_plan.ncols == NCREAL, "padded col count");
static_assert(h_plan.ok, "perm bijection onto [0,4844)");
__device__ const Plan g_plan = make_plan();

// ---------------------------------------------------------------------------
typedef __attribute__((ext_vector_type(8))) short    bf16x8;
typedef __attribute__((ext_vector_type(4))) float    f32x4;
typedef __attribute__((ext_vector_type(4))) unsigned uint4v;

__device__ inline unsigned bfpack2(float lo, float hi) {
    unsigned ul = __float_as_uint(lo), uh = __float_as_uint(hi);
    ul = (ul + 0x7fffu + ((ul >> 16) & 1u)) >> 16;
    uh = (uh + 0x7fffu + ((uh >> 16) & 1u)) & 0xffff0000u;
    return ul | uh;
}

// ---------------------------------------------------------------------------
// W fp32 [256][4844] -> bf16 [256][NK], column-permuted, pads zero-filled
// ---------------------------------------------------------------------------
__global__ __launch_bounds__(256) void wconv_kernel(
    const float* __restrict__ W, unsigned* __restrict__ Wb)
{
    const int r = blockIdx.x;
    const float* Wr = W + (size_t)r * MTOT;
    for (int i = threadIdx.x; i < NK / 2; i += 256) {
        const int m0 = g_plan.perm[2 * i], m1 = g_plan.perm[2 * i + 1];
        const float f0 = (m0 >= 0) ? Wr[m0] : 0.f;
        const float f1 = (m1 >= 0) ? Wr[m1] : 0.f;
        Wb[(size_t)r * (NK / 2) + i] = bfpack2(f0, f1);
    }
}

// ---------------------------------------------------------------------------
// Fused: tanh -> run-structured expansion (waves 0-3) -> MFMA (waves 4-7)
//   BM=64, BN=256, BK=64. grid 256, 512 thr. 8-slot As ring, barrier per
//   4-chunk interval. As is k-major [slot][granule][row][8] (min-phase LDS).
// ---------------------------------------------------------------------------
#define T_BYTES   (64 * TROW * 4)                 // 39680
#define AS_BYTES  (8 * 8 * 64 * 8 * 2)            // 65536
#define LDS_BYTES (T_BYTES + AS_BYTES)            // 105216

__global__ __launch_bounds__(512, 2) void fused_kernel(
    const float* __restrict__ x,
    const unsigned short* __restrict__ Wb,
    const float* __restrict__ bias,
    float* __restrict__ C)
{
    extern __shared__ char smem[];
    float* T = (float*)smem;
    unsigned short* As = (unsigned short*)(smem + T_BYTES);  // [slot][g][row][8]

    const int t = threadIdx.x, l = t & 63, wid = t >> 6;
    const size_t m0 = (size_t)blockIdx.x * 64;

    // producer: per-interval plan registers (wave-uniform addresses)
    uint4v ePA[4], ePB[4];
    auto loadPlan = [&](int iv, uint4v (&e)[4]) {
#pragma unroll
        for (int cc = 0; cc < 4; ++cc)
            e[cc] = *(const uint4v*)(g_plan.cplan + (iv * 4 + cc) * 16 + wid * 4);
    };
    // consumer: B fragments direct from L2-resident Wb, double-buffered
    const int w = wid - 4, lr = l & 15, lk = l >> 4;
    const unsigned short* wbase = Wb + (size_t)(w * 64 + lr) * NK + lk * 8;
    bf16x8 bA[4][2], bB[4][2];
    auto prefB = [&](int c, bf16x8 (&bf)[4][2]) {
#pragma unroll
        for (int ni = 0; ni < 4; ++ni)
#pragma unroll
            for (int ks = 0; ks < 2; ++ks)
                bf[ni][ks] = *(const bf16x8*)(wbase + (size_t)ni * 16 * NK
                                              + (size_t)c * 64 + ks * 32);
    };
    if (wid < 4) loadPlan(0, ePA); else prefB(0, bA);

    // --- prologue: deg1 tanh at permuted positions ------------------------
#pragma unroll
    for (int i = 0; i < 2; ++i) {
        const int v = t * 2 + i;                  // 0..1023
        const int r = v >> 4, f = v & 15;
        const int pf = 17 * f - f * (f - 1) / 2;  // pos_x(f)
        T[r * TROW + pf] = tanhf(x[(m0 + r) * NF + f]);
    }
    if (t < 64) { T[t*TROW + 152] = 1.f; T[t*TROW + 153] = 0.f; T[t*TROW + 154] = 0.f; }
    __syncthreads();
    // --- deg2 -------------------------------------------------------------
    {
        const int r = t >> 3, s = t & 7, base = r * TROW;
#pragma unroll
        for (int i = 0; i < 17; ++i) {
            const unsigned e = g_plan.d2t[s + 8 * i];
            T[base + (e >> 20)] = T[base + (e & 1023u)] * T[base + ((e >> 10) & 1023u)];
        }
    }
    __syncthreads();

    // --- producer expand: lane = row; quad = (uniform L, consecutive R) ---
    const int pb = l * TROW;
    auto expand = [&](int c, const uint4v& e) {
        float v[16];
#pragma unroll
        for (int q = 0; q < 4; ++q) {
            const unsigned eq = e[q];
            const float lv = T[pb + (eq & 0xffffu)];
            const int   r0 = pb + (int)(eq >> 16);
#pragma unroll
            for (int u = 0; u < 4; ++u) v[q * 4 + u] = lv * T[r0 + u];
        }
        uint4v o0, o1;
        o0[0]=bfpack2(v[0],v[1]);   o0[1]=bfpack2(v[2],v[3]);
        o0[2]=bfpack2(v[4],v[5]);   o0[3]=bfpack2(v[6],v[7]);
        o1[0]=bfpack2(v[8],v[9]);   o1[1]=bfpack2(v[10],v[11]);
        o1[2]=bfpack2(v[12],v[13]); o1[3]=bfpack2(v[14],v[15]);
        const int slot = c & 7;
        *(uint4v*)&As[(((slot * 8 + 2 * wid    ) * 64) + l) * 8] = o0;
        *(uint4v*)&As[(((slot * 8 + 2 * wid + 1) * 64) + l) * 8] = o1;
    };

    f32x4 acc[4][4];
#pragma unroll
    for (int i = 0; i < 4; ++i)
#pragma unroll
        for (int j = 0; j < 4; ++j) acc[i][j] = (f32x4){0.f, 0.f, 0.f, 0.f};

    auto domfma = [&](int c, bf16x8 (&bf)[4][2]) {
        const int slot = c & 7;
        bf16x8 af[4][2];
#pragma unroll
        for (int mi = 0; mi < 4; ++mi)
#pragma unroll
            for (int ks = 0; ks < 2; ++ks)
                af[mi][ks] = *(const bf16x8*)
                    &As[(((slot * 8 + ks * 4 + lk) * 64) + mi * 16 + lr) * 8];
#pragma unroll
        for (int ks = 0; ks < 2; ++ks)
#pragma unroll
            for (int mi = 0; mi < 4; ++mi)
#pragma unroll
                for (int ni = 0; ni < 4; ++ni)
                    acc[mi][ni] = __builtin_amdgcn_mfma_f32_16x16x32_bf16(
                        af[mi][ks], bf[ni][ks], acc[mi][ni], 0, 0, 0);
    };

    auto pbody = [&](int i, uint4v (&eUse)[4], uint4v (&eLoad)[4]) {
        if (i + 1 < NIV) {
#pragma unroll
            for (int cc = 0; cc < 4; ++cc) expand((i + 1) * 4 + cc, eUse[cc]);
        }
        if (i + 2 < NIV) loadPlan(i + 2, eLoad);
    };
    auto cbody = [&](int i) {
#pragma unroll
        for (int cc = 0; cc < 4; ++cc) {
            const int c = i * 4 + cc;
            const int nc = (c + 1 < NCHUNK) ? c + 1 : c;
            if (cc & 1) { prefB(nc, bA); domfma(c, bB); }
            else        { prefB(nc, bB); domfma(c, bA); }
        }
    };

    // pre-loop: interval 0 expanded, interval-1 plan loading
    if (wid < 4) {
#pragma unroll
        for (int cc = 0; cc < 4; ++cc) expand(cc, ePA[cc]);
        loadPlan(1, ePB);
    }
    __syncthreads();

    for (int i2 = 0; i2 < NIV; i2 += 2) {
        if (wid < 4) pbody(i2, ePB, ePA); else cbody(i2);
        __syncthreads();
        if (wid < 4) pbody(i2 + 1, ePA, ePB); else cbody(i2 + 1);
        __syncthreads();
    }

    // --- epilogue: consumers store bias+relu ------------------------------
    if (wid >= 4) {
#pragma unroll
        for (int ni = 0; ni < 4; ++ni) {
            const int col = w * 64 + ni * 16 + lr;
            const float bv = bias[col];
#pragma unroll
            for (int mi = 0; mi < 4; ++mi) {
                const size_t r0 = m0 + mi * 16 + lk * 4;
#pragma unroll
                for (int j = 0; j < 4; ++j)
                    C[(r0 + j) * OUTD + col] = fmaxf(acc[mi][ni][j] + bv, 0.f);
            }
        }
    }
}

// ---------------------------------------------------------------------------
// Launch
// ---------------------------------------------------------------------------
extern "C" void kernel_launch(void* const* d_in, const int* in_sizes, int n_in,
                              void* d_out, int out_size, void* d_ws, size_t ws_size,
                              hipStream_t stream)
{
    const float* x    = (const float*)d_in[0];
    const float* W    = (const float*)d_in[1];
    const float* bias = (const float*)d_in[2];
    float* out        = (float*)d_out;

    unsigned* Wb = (unsigned*)d_ws;              // 2.62 MB bf16 permuted W
    (void)hipFuncSetAttribute((const void*)fused_kernel,
                              hipFuncAttributeMaxDynamicSharedMemorySize, LDS_BYTES);
    wconv_kernel<<<OUTD, 256, 0, stream>>>(W, Wb);
    fused_kernel<<<BATCH / 64, 512, LDS_BYTES, stream>>>(
        x, (const unsigned short*)Wb, bias, out);
}